// Round 5
// baseline (500.854 us; speedup 1.0000x reference)
//
#include <hip/hip_runtime.h>

#define N_USERS 200000
#define N_ITEMS 100000
#define NTOT    300000
#define D       64
#define NEDGE   1200000
#define CAP     32          // fixed bucket capacity (Poisson(4): P(deg>=32) ~ 1e-26)
#define NBLK    2048        // gather blocks (8192 waves x 16 rows/group, 18750 groups)
#define NWAVE   (NBLK * 4)

typedef short short8 __attribute__((ext_vector_type(8)));
typedef float f32x4  __attribute__((ext_vector_type(4)));

__device__ __forceinline__ short f2bf(float f) {
    unsigned u = __float_as_uint(f);
    unsigned r = (u + 0x7fff + ((u >> 16) & 1)) >> 16;   // RTNE
    return (short)r;
}

__global__ void zero_ints(int* __restrict__ p, int n) {
    int i = blockIdx.x * blockDim.x + threadIdx.x;
    if (i < n) p[i] = 0;
}

// ---------------------------------------------------------------------------
// FIXED-CAP PATH: bucket edges at r*CAP + pos
// ---------------------------------------------------------------------------
__global__ void scatter_build_fixed(const int* __restrict__ rows,
                                    const int* __restrict__ cols,
                                    const float* __restrict__ vals,
                                    int* __restrict__ cursor,
                                    int2* __restrict__ edge_data) {
    int e = blockIdx.x * blockDim.x + threadIdx.x;
    if (e >= NEDGE) return;
    int r = rows[e];
    int pos = atomicAdd(&cursor[r], 1);
    if (pos < CAP)
        edge_data[(size_t)r * CAP + pos] = make_int2(cols[e], __float_as_int(vals[e]));
}

// ---------------------------------------------------------------------------
// Fused gather+finalize v5. One wave owns 16 rows per group:
//  - 4 runs of the v4 gather (4 edge slots x 16-lane float4)
//  - x -> bf16 -> per-wave LDS tile (stride 72 shorts; wave-private, no barrier)
//  - matvec via 8x mfma_f32_16x16x32_bf16 with filt B-frags staged once/block
// Fragment layouts (HW-verified, learn_hip m89/m91/m120):
//   A[m = lane&15][k = (lane>>4)*8 + j]   (j = 0..7)
//   B[k = (lane>>4)*8 + j][n = lane&15]
//   D: col = lane&15, row = (lane>>4)*4 + reg
// ---------------------------------------------------------------------------
__global__ __launch_bounds__(256)
void gather_finalize_v5(const int* __restrict__ cnt,
                        const int2* __restrict__ edge_data,
                        const float* __restrict__ user_emb,
                        const float* __restrict__ item_emb,
                        const float* __restrict__ filt,
                        float* __restrict__ out) {
    __shared__ short bsh[8][512];        // 8 B-frags (n*2+t), lane-major, 8KB
    __shared__ short xsh[4][16 * 72];    // per-wave x tile, 16 rows x 64 (+8 pad)

    int tid  = threadIdx.x;
    int w    = tid >> 6;
    int lane = tid & 63;
    int slot = lane >> 4;
    int q    = lane & 15;

    // ---- stage filt B-fragments: wave w builds frags 2w (t=0), 2w+1 (t=1) ----
    {
        int n = w;
        #pragma unroll
        for (int t = 0; t < 2; ++t) {
            int f = n * 2 + t;
            #pragma unroll
            for (int j = 0; j < 8; ++j) {
                int k    = t * 32 + (lane >> 4) * 8 + j;
                int colj = n * 16 + (lane & 15);
                bsh[f][lane * 8 + j] = f2bf(filt[k * D + colj]);
            }
        }
    }
    __syncthreads();

    int gw = blockIdx.x * 4 + w;
    const int ngroups = NTOT / 16;       // 18750

    for (int g = gw; g < ngroups; g += NWAVE) {
        int row0 = g * 16;

        // all 16 counts up front (independent broadcast loads)
        int call[16];
        #pragma unroll
        for (int i = 0; i < 16; ++i) {
            int cc = cnt[row0 + i];
            call[i] = cc < CAP ? cc : CAP;
        }

        #pragma unroll
        for (int sub = 0; sub < 4; ++sub) {
            int rbase = row0 + sub * 4;
            const int* c = &call[sub * 4];

            float4 acc[4];
            #pragma unroll
            for (int r = 0; r < 4; ++r) acc[r] = make_float4(0.f, 0.f, 0.f, 0.f);

            int cmax = max(max(c[0], c[1]), max(c[2], c[3]));

            for (int t = 0; t < cmax; t += 4) {
                #pragma unroll
                for (int r = 0; r < 4; ++r) {
                    if (t < c[r]) {                    // wave-uniform branch
                        int i = t + slot;
                        int2 ed = edge_data[(size_t)(rbase + r) * CAP + i];
                        bool valid = i < c[r];
                        int col   = valid ? ed.x : 0;
                        float val = valid ? __int_as_float(ed.y) : 0.f;
                        const float* src = (col < N_USERS)
                            ? (user_emb + (size_t)col * D)
                            : (item_emb + (size_t)(col - N_USERS) * D);
                        float4 v = ((const float4*)src)[q];
                        acc[r].x += val * v.x;
                        acc[r].y += val * v.y;
                        acc[r].z += val * v.z;
                        acc[r].w += val * v.w;
                    }
                }
            }

            // reduce the 4 slots -> every lane has all 4 row totals
            #pragma unroll
            for (int r = 0; r < 4; ++r) {
                acc[r].x += __shfl_xor(acc[r].x, 16, 64);
                acc[r].y += __shfl_xor(acc[r].y, 16, 64);
                acc[r].z += __shfl_xor(acc[r].z, 16, 64);
                acc[r].w += __shfl_xor(acc[r].w, 16, 64);
                acc[r].x += __shfl_xor(acc[r].x, 32, 64);
                acc[r].y += __shfl_xor(acc[r].y, 32, 64);
                acc[r].z += __shfl_xor(acc[r].z, 32, 64);
                acc[r].w += __shfl_xor(acc[r].w, 32, 64);
            }

            // slot owns row rbase+slot: emb load/store, x = 2e - agg -> bf16 LDS
            int myrow = rbase + slot;
            const float* esrc = (myrow < N_USERS)
                ? (user_emb + (size_t)myrow * D)
                : (item_emb + (size_t)(myrow - N_USERS) * D);
            float4 e4 = ((const float4*)esrc)[q];
            ((float4*)(out + (size_t)myrow * 128))[q] = e4;

            float4 a4;
            a4.x = slot == 0 ? acc[0].x : slot == 1 ? acc[1].x : slot == 2 ? acc[2].x : acc[3].x;
            a4.y = slot == 0 ? acc[0].y : slot == 1 ? acc[1].y : slot == 2 ? acc[2].y : acc[3].y;
            a4.z = slot == 0 ? acc[0].z : slot == 1 ? acc[1].z : slot == 2 ? acc[2].z : acc[3].z;
            a4.w = slot == 0 ? acc[0].w : slot == 1 ? acc[1].w : slot == 2 ? acc[2].w : acc[3].w;

            float xv0 = 2.f * e4.x - a4.x;
            float xv1 = 2.f * e4.y - a4.y;
            float xv2 = 2.f * e4.z - a4.z;
            float xv3 = 2.f * e4.w - a4.w;

            uint2 pk;
            pk.x = (unsigned)(unsigned short)f2bf(xv0) |
                   ((unsigned)(unsigned short)f2bf(xv1) << 16);
            pk.y = (unsigned)(unsigned short)f2bf(xv2) |
                   ((unsigned)(unsigned short)f2bf(xv3) << 16);
            int row_local = sub * 4 + slot;
            *(uint2*)&xsh[w][row_local * 72 + q * 4] = pk;   // 8B, wave-private
        }

        // ---- MFMA matvec: 16 rows x 64 cols, K=64 ----
        const short8 a0 = *(const short8*)&xsh[w][(lane & 15) * 72 +      (lane >> 4) * 8];
        const short8 a1 = *(const short8*)&xsh[w][(lane & 15) * 72 + 32 + (lane >> 4) * 8];

        f32x4 dacc[4];
        #pragma unroll
        for (int n = 0; n < 4; ++n) {
            short8 b0 = *(const short8*)&bsh[n * 2 + 0][lane * 8];
            short8 b1 = *(const short8*)&bsh[n * 2 + 1][lane * 8];
            f32x4 z = {0.f, 0.f, 0.f, 0.f};
            dacc[n] = __builtin_amdgcn_mfma_f32_16x16x32_bf16(a0, b0, z, 0, 0, 0);
            dacc[n] = __builtin_amdgcn_mfma_f32_16x16x32_bf16(a1, b1, dacc[n], 0, 0, 0);
        }

        // D: row = (lane>>4)*4 + p, col = n*16 + (lane&15); sigmoid + store
        #pragma unroll
        for (int p = 0; p < 4; ++p) {
            int row = (lane >> 4) * 4 + p;
            #pragma unroll
            for (int n = 0; n < 4; ++n) {
                int j = n * 16 + (lane & 15);
                float m = dacc[n][p];
                out[(size_t)(row0 + row) * 128 + 64 + j] = 1.f / (1.f + __expf(-m));
            }
        }
    }
}

// ---------------------------------------------------------------------------
// COMPACT PATH (fallback): histogram -> alloc -> bucket -> readlane gather
// ---------------------------------------------------------------------------
__global__ void edge_histogram(const int* __restrict__ rows,
                               int* __restrict__ counts) {
    int e = blockIdx.x * blockDim.x + threadIdx.x;
    if (e < NEDGE) atomicAdd(&counts[rows[e]], 1);
}

__global__ void alloc_ranges(const int* __restrict__ counts,
                             int* __restrict__ start,
                             int* __restrict__ cursor,
                             int* __restrict__ gcursor) {
    int r = blockIdx.x * blockDim.x + threadIdx.x;
    if (r >= NTOT) return;
    int c = counts[r];
    int s = atomicAdd(gcursor, c);
    start[r]  = s;
    cursor[r] = s;
}

__global__ void scatter_build_compact(const int* __restrict__ rows,
                                      const int* __restrict__ cols,
                                      const float* __restrict__ vals,
                                      int* __restrict__ cursor,
                                      int2* __restrict__ edge_data) {
    int e = blockIdx.x * blockDim.x + threadIdx.x;
    if (e >= NEDGE) return;
    int r = rows[e];
    int pos = atomicAdd(&cursor[r], 1);
    edge_data[pos] = make_int2(cols[e], __float_as_int(vals[e]));
}

__global__ __launch_bounds__(256)
void gather_finalize_compact(const int* __restrict__ start,
                             const int* __restrict__ cnt,
                             const int2* __restrict__ edge_data,
                             const float* __restrict__ user_emb,
                             const float* __restrict__ item_emb,
                             const float* __restrict__ filt,
                             float* __restrict__ out) {
    __shared__ float filt_sh[D * D];
    int tid = threadIdx.x;
    #pragma unroll
    for (int k = 0; k < 16; ++k)
        filt_sh[tid + k * 256] = filt[tid + k * 256];
    __syncthreads();

    int w  = tid >> 6;
    int j  = tid & 63;
    int gw = blockIdx.x * 4 + w;
    const int ngroups = NTOT / 4;

    for (int g = gw; g < ngroups; g += NWAVE) {
        int row0 = g * 4;
        float x[4], m[4];
        #pragma unroll
        for (int r = 0; r < 4; ++r) {
            int row = row0 + r;
            int s = start[row];
            int c = cnt[row];
            float acc = 0.f;
            for (int i = 0; i < c; ++i) {
                int2 ed = edge_data[s + i];
                int col = ed.x;
                float val = __int_as_float(ed.y);
                const float* src = (col < N_USERS)
                    ? (user_emb + (size_t)col * D)
                    : (item_emb + (size_t)(col - N_USERS) * D);
                acc += val * src[j];
            }
            const float* esrc = (row < N_USERS)
                ? (user_emb + (size_t)row * D)
                : (item_emb + (size_t)(row - N_USERS) * D);
            float e = esrc[j];
            out[(size_t)row * 128 + j] = e;
            x[r] = 2.f * e - acc;
            m[r] = 0.f;
        }
        #pragma unroll
        for (int k = 0; k < D; ++k) {
            float f = filt_sh[k * D + j];
            #pragma unroll
            for (int r = 0; r < 4; ++r) {
                float xk = __uint_as_float(
                    __builtin_amdgcn_readlane(__float_as_uint(x[r]), k));
                m[r] += xk * f;
            }
        }
        #pragma unroll
        for (int r = 0; r < 4; ++r)
            out[(size_t)(row0 + r) * 128 + 64 + j] = 1.f / (1.f + __expf(-m[r]));
    }
}

// ---------------------------------------------------------------------------
// LAST-RESORT fallback (no usable ws): atomic path
// ---------------------------------------------------------------------------
__global__ void init_out_full(const float* __restrict__ user_emb,
                              const float* __restrict__ item_emb,
                              float* __restrict__ out) {
    int idx = blockIdx.x * blockDim.x + threadIdx.x;
    const int total = NTOT * 32;
    if (idx >= total) return;
    int row = idx >> 5;
    int q   = idx & 31;
    float4* dst = (float4*)out + (size_t)row * 32 + q;
    if (q < 16) {
        const float* src = (row < N_USERS)
            ? (user_emb + (size_t)row * D)
            : (item_emb + (size_t)(row - N_USERS) * D);
        *dst = ((const float4*)src)[q];
    } else {
        *dst = make_float4(0.f, 0.f, 0.f, 0.f);
    }
}

__global__ void scatter_edges(const int* __restrict__ rows,
                              const int* __restrict__ cols,
                              const float* __restrict__ vals,
                              const float* __restrict__ user_emb,
                              const float* __restrict__ item_emb,
                              float* __restrict__ out) {
    long long gid = (long long)blockIdx.x * blockDim.x + threadIdx.x;
    const long long total = (long long)NEDGE * 16;
    if (gid >= total) return;
    int e = (int)(gid >> 4);
    int t = (int)(gid & 15);
    int col  = cols[e];
    int row  = rows[e];
    float val = vals[e];
    const float* src = (col < N_USERS)
        ? (user_emb + (size_t)col * D)
        : (item_emb + (size_t)(col - N_USERS) * D);
    float4 v = ((const float4*)src)[t];
    float* dst = out + (size_t)row * 128 + 64 + t * 4;
    atomicAdd(dst + 0, val * v.x);
    atomicAdd(dst + 1, val * v.y);
    atomicAdd(dst + 2, val * v.z);
    atomicAdd(dst + 3, val * v.w);
}

__global__ void finalize_rows(const float* __restrict__ filt,
                              float* __restrict__ out) {
    __shared__ float filt_sh[D * D];
    __shared__ float x_sh[4 * D];
    int tid = threadIdx.x;
    #pragma unroll
    for (int k = 0; k < 16; ++k)
        filt_sh[tid + k * 256] = filt[tid + k * 256];
    int row = blockIdx.x * 4 + (tid >> 6);
    int j   = tid & 63;
    float e = out[(size_t)row * 128 + j];
    float a = out[(size_t)row * 128 + 64 + j];
    x_sh[tid] = 2.f * e - a;
    __syncthreads();
    const float* xr = &x_sh[(tid >> 6) * D];
    float acc = 0.f;
    #pragma unroll 8
    for (int k = 0; k < D; ++k)
        acc += xr[k] * filt_sh[k * D + j];
    out[(size_t)row * 128 + 64 + j] = 1.f / (1.f + expf(-acc));
}

extern "C" void kernel_launch(void* const* d_in, const int* in_sizes, int n_in,
                              void* d_out, int out_size, void* d_ws, size_t ws_size,
                              hipStream_t stream) {
    const int*   adj_rows = (const int*)d_in[0];
    const int*   adj_cols = (const int*)d_in[1];
    const float* adj_vals = (const float*)d_in[2];
    const float* user_emb = (const float*)d_in[3];
    const float* item_emb = (const float*)d_in[4];
    const float* filt     = (const float*)d_in[5];
    float* out = (float*)d_out;

    const size_t ws_fixed   = (size_t)NTOT * 4 + (size_t)NTOT * CAP * 8;   // 78 MB
    const size_t ws_compact = (size_t)(3 * NTOT + 4) * 4 + (size_t)NEDGE * 8;

    if (ws_size >= ws_fixed) {
        int*  cursor    = (int*)d_ws;
        int2* edge_data = (int2*)((char*)d_ws + (size_t)NTOT * 4);

        zero_ints<<<(NTOT + 255) / 256, 256, 0, stream>>>(cursor, NTOT);
        scatter_build_fixed<<<(NEDGE + 255) / 256, 256, 0, stream>>>(
            adj_rows, adj_cols, adj_vals, cursor, edge_data);
        gather_finalize_v5<<<NBLK, 256, 0, stream>>>(
            cursor, edge_data, user_emb, item_emb, filt, out);
    } else if (ws_size >= ws_compact) {
        int* ws_i    = (int*)d_ws;
        int* counts  = ws_i;
        int* start   = ws_i + NTOT;
        int* cursor  = ws_i + 2 * NTOT;
        int* gcursor = ws_i + 3 * NTOT;
        int2* edge_data = (int2*)(ws_i + 3 * NTOT + 4);

        zero_ints<<<(NTOT + 255) / 256, 256, 0, stream>>>(counts, NTOT);
        zero_ints<<<1, 64, 0, stream>>>(gcursor, 1);
        edge_histogram<<<(NEDGE + 255) / 256, 256, 0, stream>>>(adj_rows, counts);
        alloc_ranges<<<(NTOT + 255) / 256, 256, 0, stream>>>(
            counts, start, cursor, gcursor);
        scatter_build_compact<<<(NEDGE + 255) / 256, 256, 0, stream>>>(
            adj_rows, adj_cols, adj_vals, cursor, edge_data);
        gather_finalize_compact<<<NBLK, 256, 0, stream>>>(
            start, counts, edge_data, user_emb, item_emb, filt, out);
    } else {
        {
            int total = NTOT * 32;
            init_out_full<<<(total + 255) / 256, 256, 0, stream>>>(
                user_emb, item_emb, out);
        }
        {
            long long total = (long long)NEDGE * 16;
            scatter_edges<<<(int)((total + 255) / 256), 256, 0, stream>>>(
                adj_rows, adj_cols, adj_vals, user_emb, item_emb, out);
        }
        finalize_rows<<<NTOT / 4, 256, 0, stream>>>(filt, out);
    }
}